// Round 5
// baseline (124.953 us; speedup 1.0000x reference)
//
#include <hip/hip_runtime.h>
#include <math.h>

#define N 4096
#define FEPS 1e-7f
#define ROWS 8
#define BLK 256
#define JT 2            // j-range split: doubles TLP (16 waves/CU vs 8)
#define FSTRIDE 12      // per-box feature record, padded to 48 B for float4 loads

// d_ws layout: [0, N*12) features | [N*12, N*12 + 512*JT*48) partial sums
#define PART_OFF (N * FSTRIDE)

// Feature record per box j (f[j*12 + k]):
// 0:conf 1:x1 2:y1 3:x2 4:y2 5:x1+x2 6:y1+y2 7:w 8:h 9:area+eps 10:atan(w/(h+eps)) 11:area
__global__ void precompute_kernel(const float* __restrict__ x, float* __restrict__ f) {
    int i = blockIdx.x * blockDim.x + threadIdx.x;
    if (i >= N) return;
    float cf = x[i * 5 + 0], x1 = x[i * 5 + 1], y1 = x[i * 5 + 2];
    float x2 = x[i * 5 + 3], y2 = x[i * 5 + 4];
    float w = x2 - x1, h = y2 - y1;
    float* fi = f + (size_t)i * FSTRIDE;
    fi[0] = cf; fi[1] = x1; fi[2] = y1; fi[3] = x2; fi[4] = y2;
    fi[5] = x1 + x2; fi[6] = y1 + y2; fi[7] = w; fi[8] = h;
    fi[9] = w * h + FEPS;
    fi[10] = atanf(w / (h + FEPS));
    fi[11] = w * h;
}

// Block (g, jt): rows g*8..g*8+7, j in [jt*2048, (jt+1)*2048), 8 iters/thread.
// Per-pair transcendentals cut to 2 (iou rcp + combined rho2/c2 + v*alpha rcp) + exp.
// iou clamped to 1.0: fast-rcp 1-ulp overshoot otherwise makes the alpha
// denominator cancel to exactly 0 on diagonal pairs -> 0*inf = NaN.
__global__ __launch_bounds__(BLK) void ciou_attn_kernel(
        const float* __restrict__ f,
        float* __restrict__ part) {
    const int tid = threadIdx.x;
    const int g = blockIdx.x / JT;
    const int jt = blockIdx.x % JT;
    const int i0 = g * ROWS;

    float rx1[ROWS], ry1[ROWS], rx2[ROWS], ry2[ROWS], rsx[ROWS], rsy[ROWS];
    float rw[ROWS], rh[ROWS], rar[ROWS], rat[ROWS], rcf[ROWS];
#pragma unroll
    for (int r = 0; r < ROWS; r++) {
        const float* fi = f + (size_t)(i0 + r) * FSTRIDE;
        rcf[r] = fi[0]; rx1[r] = fi[1]; ry1[r] = fi[2]; rx2[r] = fi[3]; ry2[r] = fi[4];
        rsx[r] = fi[5]; rsy[r] = fi[6]; rw[r] = fi[7]; rh[r] = fi[8];
        rar[r] = fi[11]; rat[r] = fi[10];
    }

    float sum[ROWS];
    float acc[ROWS][5];
#pragma unroll
    for (int r = 0; r < ROWS; r++) {
        sum[r] = 0.f;
#pragma unroll
        for (int c = 0; c < 5; c++) acc[r][c] = 0.f;
    }

    const float K = 0.4052847345693511f;  // 4/pi^2
    const float ONEP = 1.f + FEPS;
    const int jend = (jt + 1) * (N / JT);

#pragma unroll 2
    for (int j = jt * (N / JT) + tid; j < jend; j += BLK) {
        const float4* fj = (const float4*)(f + (size_t)j * FSTRIDE);
        float4 A = fj[0], B = fj[1], C = fj[2];
        float jcf = A.x, jx1 = A.y, jy1 = A.z, jx2 = A.w;
        float jy2 = B.x, jsx = B.y, jsy = B.z, jw = B.w;
        float jh = C.x, jar2 = C.y, jat = C.z;
#pragma unroll
        for (int r = 0; r < ROWS; r++) {
            float iwr = fminf(rx2[r], jx2) - fmaxf(rx1[r], jx1);
            float ihr = fminf(ry2[r], jy2) - fmaxf(ry1[r], jy1);
            float iw = fmaxf(iwr, 0.f);
            float ih = fmaxf(ihr, 0.f);
            float inter = iw * ih;
            float uni = (rar[r] + jar2) - inter;  // jar2 = area_j + eps
            float iou = fminf(inter * __builtin_amdgcn_rcpf(uni), 1.0f);
            float cw = (rw[r] + jw) - iwr;        // enclosing box via identity
            float ch = (rh[r] + jh) - ihr;
            float c2 = cw * cw + ch * ch + FEPS;
            float dx = jsx - rsx[r];
            float dy = jsy - rsy[r];
            float rho2 = (dx * dx + dy * dy) * 0.25f;
            float da = jat - rat[r];
            float v = K * da * da;
            float den = (v - iou) + ONEP;
            // rho2/c2 + v*v/den = (rho2*den + v*v*c2) / (c2*den): one rcp, not two
            float numer = rho2 * den + (v * v) * c2;
            float ciou = iou - numer * __builtin_amdgcn_rcpf(c2 * den);
            float e = __expf(ciou * rcf[r] * jcf);  // score in (-3,1]: no max-sub
            sum[r] += e;
            acc[r][0] += e * jcf;
            acc[r][1] += e * jx1;
            acc[r][2] += e * jy1;
            acc[r][3] += e * jx2;
            acc[r][4] += e * jy2;
        }
    }

    // Wave shuffle reduction (width 64) then cross-wave via LDS.
    __shared__ float red[BLK / 64][ROWS * 6];
    const int wave = tid >> 6;
    const int lane = tid & 63;
#pragma unroll
    for (int r = 0; r < ROWS; r++) {
        float v6[6] = {sum[r], acc[r][0], acc[r][1], acc[r][2], acc[r][3], acc[r][4]};
#pragma unroll
        for (int k = 0; k < 6; k++) {
            float val = v6[k];
#pragma unroll
            for (int off = 32; off > 0; off >>= 1) val += __shfl_down(val, off, 64);
            if (lane == 0) red[wave][r * 6 + k] = val;
        }
    }
    __syncthreads();
    if (tid < ROWS * 6) {
        float tot = 0.f;
#pragma unroll
        for (int w = 0; w < BLK / 64; w++) tot += red[w][tid];
        part[(size_t)blockIdx.x * (ROWS * 6) + tid] = tot;
    }
}

// One thread per output element: combine JT partials, softmax-divide, sigmoid.
__global__ void epilogue_kernel(const float* __restrict__ x,
                                const float* __restrict__ gamma,
                                const float* __restrict__ part,
                                float* __restrict__ out) {
    int idx = blockIdx.x * blockDim.x + threadIdx.x;
    if (idx >= N * 5) return;
    int i = idx / 5, c = idx % 5;
    int g = i >> 3, r = i & 7;
    float se = 0.f, a = 0.f;
#pragma unroll
    for (int jt = 0; jt < JT; jt++) {
        const float* p = part + (size_t)(g * JT + jt) * (ROWS * 6) + r * 6;
        se += p[0];
        a += p[1 + c];
    }
    float xp = x[idx] * gamma[0] + a / se;
    out[idx] = 1.f / (1.f + expf(-xp));
}

extern "C" void kernel_launch(void* const* d_in, const int* in_sizes, int n_in,
                              void* d_out, int out_size, void* d_ws, size_t ws_size,
                              hipStream_t stream) {
    const float* x = (const float*)d_in[0];
    const float* gamma = (const float*)d_in[1];
    float* out = (float*)d_out;
    float* f = (float*)d_ws;                 // N*12 floats
    float* part = (float*)d_ws + PART_OFF;   // (N/ROWS)*JT*48 floats

    precompute_kernel<<<(N + 255) / 256, 256, 0, stream>>>(x, f);
    ciou_attn_kernel<<<(N / ROWS) * JT, BLK, 0, stream>>>(f, part);
    epilogue_kernel<<<(N * 5 + 255) / 256, 256, 0, stream>>>(x, gamma, part, out);
}

// Round 6
// 111.615 us; speedup vs baseline: 1.1195x; 1.1195x over previous
//
#include <hip/hip_runtime.h>
#include <math.h>

#define N 4096
#define FEPS 1e-7f
#define ROWS 8
#define BLK 256
#define JT 2            // j-range split: 1024 blocks -> 4 blocks/CU resident
#define FSTRIDE 12      // per-box feature record, padded to 48 B for float4 loads

// d_ws layout: [0, N*12) features | then (N/ROWS)*JT*48 partial floats
#define PART_OFF (N * FSTRIDE)

// Feature record per box j (f[j*12 + k]):
// 0:conf 1:x1 2:y1 3:x2 4:y2 5:(x1+x2)/2 6:(y1+y2)/2 7:w 8:h
// 9:area+eps 10:(2/pi)*atan(w/(h+eps)) 11:area
// K=4/pi^2 is folded into the stored atan; the /4 of rho2 into the half-sums.
__global__ void precompute_kernel(const float* __restrict__ x, float* __restrict__ f) {
    int i = blockIdx.x * blockDim.x + threadIdx.x;
    if (i >= N) return;
    float cf = x[i * 5 + 0], x1 = x[i * 5 + 1], y1 = x[i * 5 + 2];
    float x2 = x[i * 5 + 3], y2 = x[i * 5 + 4];
    float w = x2 - x1, h = y2 - y1;
    float* fi = f + (size_t)i * FSTRIDE;
    fi[0] = cf; fi[1] = x1; fi[2] = y1; fi[3] = x2; fi[4] = y2;
    fi[5] = (x1 + x2) * 0.5f; fi[6] = (y1 + y2) * 0.5f; fi[7] = w; fi[8] = h;
    fi[9] = w * h + FEPS;
    fi[10] = 0.6366197723675814f * atanf(w / (h + FEPS));  // sqrt(4/pi^2)*atan
    fi[11] = w * h;
}

// Block (g, jt): rows g*8..g*8+7, j in [jt*2048, (jt+1)*2048).
// Inner body identical op-structure to round 4 (VGPR=80 known-good; the
// merged-rcp variant blew VGPR to 136 and halved occupancy — round 5).
// __launch_bounds__(BLK,4) pins the allocator under the 128-VGPR cliff.
// iou clamped to 1.0: fast-rcp 1-ulp overshoot otherwise makes the alpha
// denominator cancel to exactly 0 on diagonal pairs -> 0*inf = NaN.
__global__ __launch_bounds__(BLK, 4) void ciou_attn_kernel(
        const float* __restrict__ f,
        float* __restrict__ part) {
    const int tid = threadIdx.x;
    const int g = blockIdx.x / JT;
    const int jt = blockIdx.x % JT;
    const int i0 = g * ROWS;

    float rx1[ROWS], ry1[ROWS], rx2[ROWS], ry2[ROWS], rsx[ROWS], rsy[ROWS];
    float rw[ROWS], rh[ROWS], rar[ROWS], rat[ROWS], rcf[ROWS];
#pragma unroll
    for (int r = 0; r < ROWS; r++) {
        const float* fi = f + (size_t)(i0 + r) * FSTRIDE;
        rcf[r] = fi[0]; rx1[r] = fi[1]; ry1[r] = fi[2]; rx2[r] = fi[3]; ry2[r] = fi[4];
        rsx[r] = fi[5]; rsy[r] = fi[6]; rw[r] = fi[7]; rh[r] = fi[8];
        rar[r] = fi[11]; rat[r] = fi[10];
    }

    float sum[ROWS];
    float acc[ROWS][5];
#pragma unroll
    for (int r = 0; r < ROWS; r++) {
        sum[r] = 0.f;
#pragma unroll
        for (int c = 0; c < 5; c++) acc[r][c] = 0.f;
    }

    const float ONEP = 1.f + FEPS;
    const int jend = (jt + 1) * (N / JT);

#pragma unroll 2
    for (int j = jt * (N / JT) + tid; j < jend; j += BLK) {
        const float4* fj = (const float4*)(f + (size_t)j * FSTRIDE);
        float4 A = fj[0], B = fj[1], C = fj[2];
        float jcf = A.x, jx1 = A.y, jy1 = A.z, jx2 = A.w;
        float jy2 = B.x, jsx = B.y, jsy = B.z, jw = B.w;
        float jh = C.x, jar2 = C.y, jat = C.z;
#pragma unroll
        for (int r = 0; r < ROWS; r++) {
            float iwr = fminf(rx2[r], jx2) - fmaxf(rx1[r], jx1);
            float ihr = fminf(ry2[r], jy2) - fmaxf(ry1[r], jy1);
            float iw = fmaxf(iwr, 0.f);
            float ih = fmaxf(ihr, 0.f);
            float inter = iw * ih;
            float uni = (rar[r] + jar2) - inter;  // jar2 = area_j + eps
            float iou = fminf(inter * __builtin_amdgcn_rcpf(uni), 1.0f);
            float cw = (rw[r] + jw) - iwr;        // enclosing box via identity
            float ch = (rh[r] + jh) - ihr;
            float c2 = cw * cw + ch * ch + FEPS;
            float dx = jsx - rsx[r];              // half-diffs: rho2 = dx^2+dy^2
            float dy = jsy - rsy[r];
            float rho2 = dx * dx + dy * dy;
            float da = jat - rat[r];              // K pre-folded into atan
            float v = da * da;
            float den = (v - iou) + ONEP;
            float valpha = v * v * __builtin_amdgcn_rcpf(den);  // v * alpha
            float ciou = iou - (rho2 * __builtin_amdgcn_rcpf(c2) + valpha);
            float e = __expf(ciou * rcf[r] * jcf);  // score in (-3,1]: no max-sub
            sum[r] += e;
            acc[r][0] += e * jcf;
            acc[r][1] += e * jx1;
            acc[r][2] += e * jy1;
            acc[r][3] += e * jx2;
            acc[r][4] += e * jy2;
        }
    }

    // Wave shuffle reduction (width 64) then cross-wave via LDS.
    __shared__ float red[BLK / 64][ROWS * 6];
    const int wave = tid >> 6;
    const int lane = tid & 63;
#pragma unroll
    for (int r = 0; r < ROWS; r++) {
        float v6[6] = {sum[r], acc[r][0], acc[r][1], acc[r][2], acc[r][3], acc[r][4]};
#pragma unroll
        for (int k = 0; k < 6; k++) {
            float val = v6[k];
#pragma unroll
            for (int off = 32; off > 0; off >>= 1) val += __shfl_down(val, off, 64);
            if (lane == 0) red[wave][r * 6 + k] = val;
        }
    }
    __syncthreads();
    if (tid < ROWS * 6) {
        float tot = 0.f;
#pragma unroll
        for (int w = 0; w < BLK / 64; w++) tot += red[w][tid];
        part[(size_t)blockIdx.x * (ROWS * 6) + tid] = tot;
    }
}

// One thread per output element: combine JT partials, softmax-divide, sigmoid.
__global__ void epilogue_kernel(const float* __restrict__ x,
                                const float* __restrict__ gamma,
                                const float* __restrict__ part,
                                float* __restrict__ out) {
    int idx = blockIdx.x * blockDim.x + threadIdx.x;
    if (idx >= N * 5) return;
    int i = idx / 5, c = idx % 5;
    int g = i >> 3, r = i & 7;
    float se = 0.f, a = 0.f;
#pragma unroll
    for (int jt = 0; jt < JT; jt++) {
        const float* p = part + (size_t)(g * JT + jt) * (ROWS * 6) + r * 6;
        se += p[0];
        a += p[1 + c];
    }
    float xp = x[idx] * gamma[0] + a / se;
    out[idx] = 1.f / (1.f + expf(-xp));
}

extern "C" void kernel_launch(void* const* d_in, const int* in_sizes, int n_in,
                              void* d_out, int out_size, void* d_ws, size_t ws_size,
                              hipStream_t stream) {
    const float* x = (const float*)d_in[0];
    const float* gamma = (const float*)d_in[1];
    float* out = (float*)d_out;
    float* f = (float*)d_ws;                 // N*12 floats
    float* part = (float*)d_ws + PART_OFF;   // (N/ROWS)*JT*48 floats

    precompute_kernel<<<(N + 255) / 256, 256, 0, stream>>>(x, f);
    ciou_attn_kernel<<<(N / ROWS) * JT, BLK, 0, stream>>>(f, part);
    epilogue_kernel<<<(N * 5 + 255) / 256, 256, 0, stream>>>(x, gamma, part, out);
}

// Round 7
// 88.186 us; speedup vs baseline: 1.4169x; 1.2657x over previous
//
#include <hip/hip_runtime.h>
#include <math.h>

#define N 4096
#define FEPS 1e-7f
#define ROWS 4          // 4 rows/block: keeps VGPR ~52-64 -> 8 waves/EU natural
#define BLK 256
#define JT 2            // j-split: (N/ROWS)*JT = 2048 blocks = 8 blocks/CU
#define FSTRIDE 12      // per-box feature record, padded to 48 B for float4 loads

// d_ws layout: [0, N*12) features | then 2048*24 partial floats
#define PART_OFF (N * FSTRIDE)

// NOTE (measured r5/r6): do NOT use the 2nd __launch_bounds__ arg here —
// (256,4) capped VGPR at 64 and spilled ~90 MB/dispatch to scratch (r6);
// and the merged-rcp body variant blew VGPR to 136 (r5). The r4 3-rcp body
// with plain bounds is the known-good register shape.

// Feature record per box j (f[j*12 + k]):
// 0:conf 1:x1 2:y1 3:x2 4:y2 5:(x1+x2)/2 6:(y1+y2)/2 7:w 8:h
// 9:area+eps 10:(2/pi)*atan(w/(h+eps)) 11:area
// K=4/pi^2 folded into the stored atan; rho2's /4 folded into half-sums.
__global__ void precompute_kernel(const float* __restrict__ x, float* __restrict__ f) {
    int i = blockIdx.x * blockDim.x + threadIdx.x;
    if (i >= N) return;
    float cf = x[i * 5 + 0], x1 = x[i * 5 + 1], y1 = x[i * 5 + 2];
    float x2 = x[i * 5 + 3], y2 = x[i * 5 + 4];
    float w = x2 - x1, h = y2 - y1;
    float* fi = f + (size_t)i * FSTRIDE;
    fi[0] = cf; fi[1] = x1; fi[2] = y1; fi[3] = x2; fi[4] = y2;
    fi[5] = (x1 + x2) * 0.5f; fi[6] = (y1 + y2) * 0.5f; fi[7] = w; fi[8] = h;
    fi[9] = w * h + FEPS;
    fi[10] = 0.6366197723675814f * atanf(w / (h + FEPS));  // (2/pi)*atan
    fi[11] = w * h;
}

// Block (g, jt): rows g*4..g*4+3, j in [jt*2048, (jt+1)*2048), 8 iters/thread.
// iou clamped to 1.0: fast-rcp 1-ulp overshoot otherwise makes the alpha
// denominator cancel to exactly 0 on diagonal pairs -> 0*inf = NaN.
__global__ __launch_bounds__(BLK) void ciou_attn_kernel(
        const float* __restrict__ f,
        float* __restrict__ part) {
    const int tid = threadIdx.x;
    const int g = blockIdx.x / JT;
    const int jt = blockIdx.x % JT;
    const int i0 = g * ROWS;

    float rx1[ROWS], ry1[ROWS], rx2[ROWS], ry2[ROWS], rsx[ROWS], rsy[ROWS];
    float rw[ROWS], rh[ROWS], rar[ROWS], rat[ROWS], rcf[ROWS];
#pragma unroll
    for (int r = 0; r < ROWS; r++) {
        const float* fi = f + (size_t)(i0 + r) * FSTRIDE;
        rcf[r] = fi[0]; rx1[r] = fi[1]; ry1[r] = fi[2]; rx2[r] = fi[3]; ry2[r] = fi[4];
        rsx[r] = fi[5]; rsy[r] = fi[6]; rw[r] = fi[7]; rh[r] = fi[8];
        rar[r] = fi[11]; rat[r] = fi[10];
    }

    float sum[ROWS];
    float acc[ROWS][5];
#pragma unroll
    for (int r = 0; r < ROWS; r++) {
        sum[r] = 0.f;
#pragma unroll
        for (int c = 0; c < 5; c++) acc[r][c] = 0.f;
    }

    const float ONEP = 1.f + FEPS;
    const int jend = (jt + 1) * (N / JT);

#pragma unroll 2
    for (int j = jt * (N / JT) + tid; j < jend; j += BLK) {
        const float4* fj = (const float4*)(f + (size_t)j * FSTRIDE);
        float4 A = fj[0], B = fj[1], C = fj[2];
        float jcf = A.x, jx1 = A.y, jy1 = A.z, jx2 = A.w;
        float jy2 = B.x, jsx = B.y, jsy = B.z, jw = B.w;
        float jh = C.x, jar2 = C.y, jat = C.z;
#pragma unroll
        for (int r = 0; r < ROWS; r++) {
            float iwr = fminf(rx2[r], jx2) - fmaxf(rx1[r], jx1);
            float ihr = fminf(ry2[r], jy2) - fmaxf(ry1[r], jy1);
            float iw = fmaxf(iwr, 0.f);
            float ih = fmaxf(ihr, 0.f);
            float inter = iw * ih;
            float uni = (rar[r] + jar2) - inter;  // jar2 = area_j + eps
            float iou = fminf(inter * __builtin_amdgcn_rcpf(uni), 1.0f);
            float cw = (rw[r] + jw) - iwr;        // enclosing box via identity
            float ch = (rh[r] + jh) - ihr;
            float c2 = cw * cw + ch * ch + FEPS;
            float dx = jsx - rsx[r];              // half-coords: rho2 = dx^2+dy^2
            float dy = jsy - rsy[r];
            float rho2 = dx * dx + dy * dy;
            float da = jat - rat[r];              // K pre-folded into atan
            float v = da * da;
            float den = (v - iou) + ONEP;
            float valpha = v * v * __builtin_amdgcn_rcpf(den);  // v * alpha
            float ciou = iou - (rho2 * __builtin_amdgcn_rcpf(c2) + valpha);
            float e = __expf(ciou * rcf[r] * jcf);  // score in (-3,1]: no max-sub
            sum[r] += e;
            acc[r][0] += e * jcf;
            acc[r][1] += e * jx1;
            acc[r][2] += e * jy1;
            acc[r][3] += e * jx2;
            acc[r][4] += e * jy2;
        }
    }

    // Wave shuffle reduction (width 64) then cross-wave via LDS.
    __shared__ float red[BLK / 64][ROWS * 6];
    const int wave = tid >> 6;
    const int lane = tid & 63;
#pragma unroll
    for (int r = 0; r < ROWS; r++) {
        float v6[6] = {sum[r], acc[r][0], acc[r][1], acc[r][2], acc[r][3], acc[r][4]};
#pragma unroll
        for (int k = 0; k < 6; k++) {
            float val = v6[k];
#pragma unroll
            for (int off = 32; off > 0; off >>= 1) val += __shfl_down(val, off, 64);
            if (lane == 0) red[wave][r * 6 + k] = val;
        }
    }
    __syncthreads();
    if (tid < ROWS * 6) {
        float tot = 0.f;
#pragma unroll
        for (int w = 0; w < BLK / 64; w++) tot += red[w][tid];
        part[(size_t)blockIdx.x * (ROWS * 6) + tid] = tot;
    }
}

// One thread per output element: combine JT partials, softmax-divide, sigmoid.
__global__ void epilogue_kernel(const float* __restrict__ x,
                                const float* __restrict__ gamma,
                                const float* __restrict__ part,
                                float* __restrict__ out) {
    int idx = blockIdx.x * blockDim.x + threadIdx.x;
    if (idx >= N * 5) return;
    int i = idx / 5, c = idx % 5;
    int g = i >> 2, r = i & 3;  // ROWS = 4
    float se = 0.f, a = 0.f;
#pragma unroll
    for (int jt = 0; jt < JT; jt++) {
        const float* p = part + (size_t)(g * JT + jt) * (ROWS * 6) + r * 6;
        se += p[0];
        a += p[1 + c];
    }
    float xp = x[idx] * gamma[0] + a / se;
    out[idx] = 1.f / (1.f + expf(-xp));
}

extern "C" void kernel_launch(void* const* d_in, const int* in_sizes, int n_in,
                              void* d_out, int out_size, void* d_ws, size_t ws_size,
                              hipStream_t stream) {
    const float* x = (const float*)d_in[0];
    const float* gamma = (const float*)d_in[1];
    float* out = (float*)d_out;
    float* f = (float*)d_ws;                 // N*12 floats = 196 KB
    float* part = (float*)d_ws + PART_OFF;   // 2048*24 floats = 196 KB

    precompute_kernel<<<(N + 255) / 256, 256, 0, stream>>>(x, f);
    ciou_attn_kernel<<<(N / ROWS) * JT, BLK, 0, stream>>>(f, part);
    epilogue_kernel<<<(N * 5 + 255) / 256, 256, 0, stream>>>(x, gamma, part, out);
}

// Round 9
// 87.770 us; speedup vs baseline: 1.4236x; 1.0047x over previous
//
#include <hip/hip_runtime.h>
#include <math.h>

#define N 4096
#define FEPS 1e-7f
#define BLK 256
#define JT 64           // j-chunks: grid = 16*64 = 1024 blocks = 4/CU, 16 waves/CU
#define CH (N / JT)     // 64 j's per block
#define FSTRIDE 12      // per-box feature record, 48 B
#define N6 (N * 6)

// d_ws layout: [0, N*12) features | part[jt][i*6+k], jt<JT : JT*N*6 floats (6.3 MB)
#define PART_OFF (N * FSTRIDE)

// Feature record per box (f[i*12 + k]):
// 0:conf 1:x1 2:y1 3:x2 4:y2 5:(x1+x2)/2 6:(y1+y2)/2 7:w 8:h
// 9:area+eps/2 10:(2/pi)*atan(w/(h+eps)) 11:conf*sqrt(log2(e))
// Folds: K=4/pi^2 into atan; rho2's /4 into half-coords; union eps split
// half/half between the two records; log2(e) for v_exp_f32 (2^x) into conf.
__global__ void precompute_kernel(const float* __restrict__ x, float* __restrict__ f) {
    int i = blockIdx.x * blockDim.x + threadIdx.x;
    if (i >= N) return;
    float cf = x[i * 5 + 0], x1 = x[i * 5 + 1], y1 = x[i * 5 + 2];
    float x2 = x[i * 5 + 3], y2 = x[i * 5 + 4];
    float w = x2 - x1, h = y2 - y1;
    float* fi = f + (size_t)i * FSTRIDE;
    fi[0] = cf; fi[1] = x1; fi[2] = y1; fi[3] = x2; fi[4] = y2;
    fi[5] = (x1 + x2) * 0.5f; fi[6] = (y1 + y2) * 0.5f; fi[7] = w; fi[8] = h;
    fi[9] = w * h + 0.5f * FEPS;
    fi[10] = 0.6366197723675814f * atanf(w / (h + FEPS));   // (2/pi)*atan
    fi[11] = cf * 1.2011224087864498f;                       // cf*sqrt(log2 e)
}

// Row-per-lane: thread owns row i = gb*256+tid; all lanes step the SAME j
// (block-uniform -> compiler emits s_load, SGPR broadcast; no VMEM latency in
// the vector path, no per-lane j-prep, and NO cross-lane reduction at all).
// Block (gb, jt) covers j in [jt*64, jt*64+64); partials to ws.
// iou clamped to 1.0: fast-rcp 1-ulp overshoot otherwise makes the alpha
// denominator cancel to exactly 0 on diagonal pairs -> 0*inf = NaN.
// NOTE (r5/r6 measured): no 2nd __launch_bounds__ arg — (256,4) forced
// VGPR=64 and spilled ~90 MB/dispatch to scratch.
__global__ __launch_bounds__(BLK) void ciou_attn_kernel(
        const float* __restrict__ f,
        float* __restrict__ part) {
    const int gb = blockIdx.x / JT;
    const int jt = blockIdx.x % JT;
    const int i = gb * BLK + threadIdx.x;

    const float4* fi = (const float4*)(f + (size_t)i * FSTRIDE);
    float4 A = fi[0], B = fi[1], C = fi[2];
    const float rx1 = A.y, ry1 = A.z, rx2 = A.w;
    const float ry2 = B.x, rhx = B.y, rhy = B.z, rw = B.w;
    const float rh = C.x, rareps = C.y, rat = C.z, rcf2 = C.w;

    float sum = 0.f, a0 = 0.f, a1 = 0.f, a2 = 0.f, a3 = 0.f, a4 = 0.f;
    const float ONEP = 1.f + FEPS;
    const float* fj = f + (size_t)(jt * CH) * FSTRIDE;

#pragma unroll 4
    for (int jj = 0; jj < CH; jj++, fj += FSTRIDE) {
        // Block-uniform j-features -> scalar loads (SGPR broadcast).
        float jcf = fj[0], jx1 = fj[1], jy1 = fj[2], jx2 = fj[3], jy2 = fj[4];
        float jhx = fj[5], jhy = fj[6], jw = fj[7], jh = fj[8];
        float jareps = fj[9], jat = fj[10], jcf2 = fj[11];

        float iwr = fminf(rx2, jx2) - fmaxf(rx1, jx1);
        float ihr = fminf(ry2, jy2) - fmaxf(ry1, jy1);
        float iw = fmaxf(iwr, 0.f);
        float ih = fmaxf(ihr, 0.f);
        float inter = iw * ih;
        float uni = (rareps + jareps) - inter;          // eps split across records
        float iou = fminf(inter * __builtin_amdgcn_rcpf(uni), 1.0f);
        float cw = (rw + jw) - iwr;                     // enclosing box identity
        float ch = (rh + jh) - ihr;
        float c2 = cw * cw + ch * ch + FEPS;
        float dx = jhx - rhx;                           // half-coords: rho2=dx^2+dy^2
        float dy = jhy - rhy;
        float rho2 = dx * dx + dy * dy;
        float da = jat - rat;                           // K pre-folded into atan
        float v = da * da;
        float den = (v - iou) + ONEP;
        float valpha = v * v * __builtin_amdgcn_rcpf(den);
        float ciou = iou - (rho2 * __builtin_amdgcn_rcpf(c2) + valpha);
        // v_exp_f32 is 2^x; log2(e) pre-folded into rcf2*jcf2 -> this is e^s.
        float e = __builtin_amdgcn_exp2f(ciou * (rcf2 * jcf2));
        sum += e;
        a0 += e * jcf;
        a1 += e * jx1;
        a2 += e * jy1;
        a3 += e * jx2;
        a4 += e * jy2;
    }

    float* p = part + (size_t)jt * N6 + (size_t)i * 6;
    p[0] = sum; p[1] = a0; p[2] = a1; p[3] = a2; p[4] = a3; p[5] = a4;
}

// One thread per output element (i,c): sum JT partials, softmax-divide, sigmoid.
__global__ void epilogue_kernel(const float* __restrict__ x,
                                const float* __restrict__ gamma,
                                const float* __restrict__ part,
                                float* __restrict__ out) {
    int idx = blockIdx.x * blockDim.x + threadIdx.x;
    if (idx >= N * 5) return;
    int i = idx / 5, c = idx % 5;
    float se = 0.f, a = 0.f;
    const float* p = part + (size_t)i * 6;
#pragma unroll 8
    for (int jt = 0; jt < JT; jt++) {
        se += p[jt * (size_t)N6 + 0];
        a  += p[jt * (size_t)N6 + 1 + c];
    }
    float xp = x[idx] * gamma[0] + a / se;
    out[idx] = 1.f / (1.f + expf(-xp));
}

extern "C" void kernel_launch(void* const* d_in, const int* in_sizes, int n_in,
                              void* d_out, int out_size, void* d_ws, size_t ws_size,
                              hipStream_t stream) {
    const float* x = (const float*)d_in[0];
    const float* gamma = (const float*)d_in[1];
    float* out = (float*)d_out;
    float* f = (float*)d_ws;                 // N*12 floats = 196 KB
    float* part = (float*)d_ws + PART_OFF;   // JT*N*6 floats = 6.3 MB

    precompute_kernel<<<(N + 255) / 256, 256, 0, stream>>>(x, f);
    ciou_attn_kernel<<<(N / BLK) * JT, BLK, 0, stream>>>(f, part);
    epilogue_kernel<<<(N * 5 + 255) / 256, 256, 0, stream>>>(x, gamma, part, out);
}

// Round 10
// 83.842 us; speedup vs baseline: 1.4903x; 1.0468x over previous
//
#include <hip/hip_runtime.h>
#include <math.h>

#define N 4096
#define FEPS 1e-7f
#define BLK 256
#define JT 64           // grid = 16*64 = 1024 blocks = 4/CU = 4 waves/SIMD
#define CH (N / JT)     // 64 j's staged in LDS per block (3 KB)
#define LSTRIDE 12
#define N6 (N * 6)

// d_ws: part[jt][i*6+k] : JT*N*6 floats = 6.3 MB. No feature table anymore.

// Per-box record (12 floats): 0:conf 1:x1 2:y1 3:x2 4:y2 5:(x1+x2)/2
// 6:(y1+y2)/2 7:w 8:h 9:area+eps/2 10:(2/pi)*atan(w/(h+eps)) 11:conf*sqrt(log2e)
// Folds: K=4/pi^2 into atan, rho2's /4 into half-coords, union-eps split
// across the two records, log2(e) for v_exp_f32 (2^x) into conf.
__device__ __forceinline__ void box_record(const float* __restrict__ x, int i, float* rec) {
    float cf = x[i * 5 + 0], x1 = x[i * 5 + 1], y1 = x[i * 5 + 2];
    float x2 = x[i * 5 + 3], y2 = x[i * 5 + 4];
    float w = x2 - x1, h = y2 - y1;
    rec[0] = cf; rec[1] = x1; rec[2] = y1; rec[3] = x2; rec[4] = y2;
    rec[5] = (x1 + x2) * 0.5f; rec[6] = (y1 + y2) * 0.5f; rec[7] = w; rec[8] = h;
    rec[9] = w * h + 0.5f * FEPS;
    rec[10] = 0.6366197723675814f * atanf(w / (h + FEPS));
    rec[11] = cf * 1.2011224087864498f;
}

// Row-per-lane, LDS-broadcast j-loop. Block (gb, jt): lane owns row
// i = gb*256+tid; j-chunk [jt*64, jt*64+64) staged in LDS by the first 64
// threads (computed in-kernel — no precompute pass, no global feature table).
// Inner loop: 12 same-address ds_read broadcasts (bank-conflict-free) + ~40
// VALU + 4 transcendental per pair; no VMEM, no cross-lane reduction.
// iou clamped to 1.0: fast-rcp 1-ulp overshoot otherwise zeroes the alpha
// denominator on diagonal pairs -> 0*inf = NaN (measured r2->r3).
// NOTE (r5/r6 measured): no 2nd __launch_bounds__ arg — (256,4) forced
// VGPR=64 and spilled ~90 MB/dispatch to scratch.
__global__ __launch_bounds__(BLK) void ciou_attn_kernel(
        const float* __restrict__ x,
        float* __restrict__ part) {
    __shared__ float jrec[CH * LSTRIDE];  // 3 KB
    const int tid = threadIdx.x;
    const int gb = blockIdx.x / JT;
    const int jt = blockIdx.x % JT;
    const int i = gb * BLK + tid;

    // Stage j-chunk into LDS (first CH threads).
    if (tid < CH) box_record(x, jt * CH + tid, &jrec[tid * LSTRIDE]);

    // Per-lane row record in registers.
    float R[12];
    box_record(x, i, R);
    const float rx1 = R[1], ry1 = R[2], rx2 = R[3], ry2 = R[4];
    const float rhx = R[5], rhy = R[6], rw = R[7], rh = R[8];
    const float rareps = R[9], rat = R[10], rcf2 = R[11];

    __syncthreads();

    float sum = 0.f, a0 = 0.f, a1 = 0.f, a2 = 0.f, a3 = 0.f, a4 = 0.f;
    const float ONEP = 1.f + FEPS;

#pragma unroll 4
    for (int jj = 0; jj < CH; jj++) {
        const float* fj = &jrec[jj * LSTRIDE];  // uniform address -> broadcast
        float jcf = fj[0], jx1 = fj[1], jy1 = fj[2], jx2 = fj[3], jy2 = fj[4];
        float jhx = fj[5], jhy = fj[6], jw = fj[7], jh = fj[8];
        float jareps = fj[9], jat = fj[10], jcf2 = fj[11];

        float iwr = fminf(rx2, jx2) - fmaxf(rx1, jx1);
        float ihr = fminf(ry2, jy2) - fmaxf(ry1, jy1);
        float iw = fmaxf(iwr, 0.f);
        float ih = fmaxf(ihr, 0.f);
        float inter = iw * ih;
        float uni = (rareps + jareps) - inter;
        float iou = fminf(inter * __builtin_amdgcn_rcpf(uni), 1.0f);
        float cw = (rw + jw) - iwr;              // enclosing box identity
        float ch = (rh + jh) - ihr;
        float c2 = fmaf(cw, cw, fmaf(ch, ch, FEPS));
        float dx = jhx - rhx;
        float dy = jhy - rhy;
        float rho2 = fmaf(dx, dx, dy * dy);      // /4 pre-folded
        float da = jat - rat;                    // K pre-folded
        float v = da * da;
        float den = (v - iou) + ONEP;
        float valpha = (v * v) * __builtin_amdgcn_rcpf(den);
        float ciou = iou - fmaf(rho2, __builtin_amdgcn_rcpf(c2), valpha);
        float e = __builtin_amdgcn_exp2f(ciou * (rcf2 * jcf2));  // e^s
        sum += e;
        a0 = fmaf(e, jcf, a0);
        a1 = fmaf(e, jx1, a1);
        a2 = fmaf(e, jy1, a2);
        a3 = fmaf(e, jx2, a3);
        a4 = fmaf(e, jy2, a4);
    }

    float* p = part + (size_t)jt * N6 + (size_t)i * 6;
    p[0] = sum; p[1] = a0; p[2] = a1; p[3] = a2; p[4] = a3; p[5] = a4;
}

// One thread per output element (i,c): sum JT partials, softmax-divide, sigmoid.
__global__ void epilogue_kernel(const float* __restrict__ x,
                                const float* __restrict__ gamma,
                                const float* __restrict__ part,
                                float* __restrict__ out) {
    int idx = blockIdx.x * blockDim.x + threadIdx.x;
    if (idx >= N * 5) return;
    int i = idx / 5, c = idx % 5;
    float se = 0.f, a = 0.f;
    const float* p = part + (size_t)i * 6;
#pragma unroll 8
    for (int jt = 0; jt < JT; jt++) {
        se += p[jt * (size_t)N6 + 0];
        a  += p[jt * (size_t)N6 + 1 + c];
    }
    float xp = x[idx] * gamma[0] + a / se;
    out[idx] = 1.f / (1.f + expf(-xp));
}

extern "C" void kernel_launch(void* const* d_in, const int* in_sizes, int n_in,
                              void* d_out, int out_size, void* d_ws, size_t ws_size,
                              hipStream_t stream) {
    const float* x = (const float*)d_in[0];
    const float* gamma = (const float*)d_in[1];
    float* out = (float*)d_out;
    float* part = (float*)d_ws;  // JT*N*6 floats = 6.3 MB

    ciou_attn_kernel<<<(N / BLK) * JT, BLK, 0, stream>>>(x, part);
    epilogue_kernel<<<(N * 5 + 255) / 256, 256, 0, stream>>>(x, gamma, part, out);
}